// Round 16
// baseline (42.758 us; speedup 1.0000x reference)
//
#include <hip/hip_runtime.h>
#include <math.h>
#include <stdint.h>

#define NB 16
#define NH 512
#define NW 512
#define PLANE (NH * NW)
#define INF_D 1.0e9f
#define INF2 1.0e18f   // == fl(1e9f*1e9f), matches reference d*d rounding
#define BIG 3.0e38f
#define NSEG 64        // 512 / 8
#define TWB 4          // tile width (cols/lines per block) -- was 8
#define HROW 516       // LDS row stride (floats)

// ---------------------------------------------------------------------------
// One 8-wide segment of the exact min-plus: best[j] = min(best[j],
// h[k] - 2*i_j*k). Exact ints < 2^24 on finite path -> bit-exact; INF2
// absorbs shifts (ulp(1e18) >> 2^20). min3-pair form.
// ---------------------------------------------------------------------------
__device__ __forceinline__ void eval_seg(const float* __restrict__ hrow,
                                         int ss, float* best,
                                         const float* neg2i) {
    const float* hp = hrow + ss * 8;
    float4 A = *reinterpret_cast<const float4*>(hp);
    float4 B = *reinterpret_cast<const float4*>(hp + 4);
    float s8f = (float)(ss * 8);
#pragma unroll
    for (int j = 0; j < 8; ++j) {
        float n2 = neg2i[j];
        float c0 = fmaf(n2, s8f, A.x);
        float c1 = fmaf(n2, s8f + 1.0f, A.y);
        float c2 = fmaf(n2, s8f + 2.0f, A.z);
        float c3 = fmaf(n2, s8f + 3.0f, A.w);
        float c4 = fmaf(n2, s8f + 4.0f, B.x);
        float c5 = fmaf(n2, s8f + 5.0f, B.y);
        float c6 = fmaf(n2, s8f + 6.0f, B.z);
        float c7 = fmaf(n2, s8f + 7.0f, B.w);
        float bb = fminf(fminf(best[j], c0), c1);
        bb = fminf(fminf(bb, c2), c3);
        bb = fminf(fminf(bb, c4), c5);
        bb = fminf(fminf(bb, c6), c7);
        best[j] = bb;
    }
}

// ---------------------------------------------------------------------------
// Window eval (R11, proven exact): home+ring1 branch-free, then sqrt(bmax)
// window evaluated unconditionally. Superset of candidates contains the
// argmin -> exact min unchanged.
// ---------------------------------------------------------------------------
__device__ __forceinline__ void eval_minplus(const float* __restrict__ hrow,
                                             int q, float* best,
                                             const float* neg2i,
                                             const float* ifl) {
    int s_lo0 = (q > 0) ? q - 1 : 0;
    int s_hi0 = (q < NSEG - 1) ? q + 1 : NSEG - 1;
    for (int ss = s_lo0; ss <= s_hi0; ++ss) eval_seg(hrow, ss, best, neg2i);

    float t0 = fmaf(ifl[0], ifl[0], best[0]);
    float t1 = fmaf(ifl[1], ifl[1], best[1]);
    float t2 = fmaf(ifl[2], ifl[2], best[2]);
    float t3 = fmaf(ifl[3], ifl[3], best[3]);
    float t4 = fmaf(ifl[4], ifl[4], best[4]);
    float t5 = fmaf(ifl[5], ifl[5], best[5]);
    float t6 = fmaf(ifl[6], ifl[6], best[6]);
    float t7 = fmaf(ifl[7], ifl[7], best[7]);
    float m = fmaxf(fmaxf(t0, t1), t2);
    m = fmaxf(fmaxf(m, t3), t4);
    m = fmaxf(fmaxf(m, t5), t6);
    float bmax = fmaxf(m, t7);

    int sw = (int)sqrtf(bmax) + 1;
    int i0 = q * 8;
    int s_lo = (i0 - sw) >> 3;
    int s_hi = (i0 + 7 + sw) >> 3;
    if (s_lo < 0) s_lo = 0;
    if (s_hi > NSEG - 1) s_hi = NSEG - 1;
    for (int ss = s_lo; ss <= s_hi; ++ss) {
        if (ss >= s_lo0 && ss <= s_hi0) continue;
        eval_seg(hrow, ss, best, neg2i);
    }
}

// ---------------------------------------------------------------------------
// K1: exact B-scan -> u8 codes (R11, unchanged). 1 col/thread, coalesced.
// code = d (0..15 finite, 31 = INF) | (isnan(x) << 7).
// ---------------------------------------------------------------------------
__global__ __launch_bounds__(256, 4) void k_pass_b(const float* __restrict__ x,
                                                   unsigned char* __restrict__ code) {
    int col = blockIdx.x * 256 + threadIdx.x;   // 1024 blocks * 256 == PLANE
    float d0[NB], dd[NB];
    int nanb = 0;
#pragma unroll
    for (int b = 0; b < NB; ++b) {
        float v = x[(size_t)b * PLANE + col];
        nanb |= (isnan(v) ? (1 << b) : 0);
        d0[b] = (v == 0.0f) ? 0.0f : INF_D;     // NaN != 0 -> foreground
    }
    float cc = INF_D;
#pragma unroll
    for (int b = 0; b < NB; ++b) { cc = fminf(cc + 1.0f, d0[b]); dd[b] = cc; }
    cc = INF_D;
#pragma unroll
    for (int b = NB - 1; b >= 0; --b) { cc = fminf(cc + 1.0f, d0[b]); dd[b] = fminf(dd[b], cc); }
#pragma unroll
    for (int b = 0; b < NB; ++b) {
        int di = (dd[b] >= 1.0e8f) ? 31 : (int)dd[b];  // exact small int
        code[(size_t)b * PLANE + col] =
            (unsigned char)(di | (((nanb >> b) & 1) << 7));
    }
}

// ---------------------------------------------------------------------------
// K2: min-plus along H. 256 thr, one (b, 4-wide w tile). Grid (128, 16) =
// 2048 blocks -> 8 independent blocks/CU (VGPR cap 64, LDS 10.3 KB) =
// 32 waves/CU with 8-way block-level overlap of syncs/staging.
// Writes fl(fl(i^2+best) + w^2) with NaN flag in sign bit.
// ---------------------------------------------------------------------------
__global__ __launch_bounds__(256, 8) void k_pass_h(const unsigned char* __restrict__ code,
                                                   float* __restrict__ out) {
    __shared__ float hs[TWB * HROW];        // 8.3 KB
    __shared__ unsigned int flgw[NH];       // 2 KB (flag byte per (k,w))
    int t = threadIdx.x;
    int b = blockIdx.y;
    int w0 = blockIdx.x * TWB;
    const unsigned char* gb8 = code + (size_t)b * PLANE + w0;

    for (int k = t; k < NH; k += 256) {
        unsigned int u = *reinterpret_cast<const unsigned int*>(gb8 + (size_t)k * NW);
        int kk = k * k;
#pragma unroll
        for (int e = 0; e < 4; ++e) {
            int c = (u >> (8 * e)) & 0xFF;
            int dl = c & 31;
            hs[e * HROW + k] = (dl == 31) ? INF2 : (float)(dl * dl + kk);
        }
        flgw[k] = (u >> 7) & 0x01010101u;   // byte idx k*4+w
    }
    __syncthreads();

    int w = t & 3, q = t >> 2;
    int i0 = q * 8;
    float best[8], neg2i[8], ifl[8];
#pragma unroll
    for (int j = 0; j < 8; ++j) {
        best[j] = BIG;
        ifl[j] = (float)(i0 + j);
        neg2i[j] = (float)(-2 * (i0 + j));
    }
    eval_minplus(&hs[w * HROW], q, best, neg2i, ifl);

    const unsigned char* flgb = reinterpret_cast<const unsigned char*>(flgw);
    float wgf = (float)(w0 + w);
    float* ob = out + (size_t)b * PLANE + w0 + w;
#pragma unroll
    for (int j = 0; j < 8; ++j) {
        float v = fmaf(ifl[j], ifl[j], best[j]);   // exact d^2 after B+H
        float v2 = fmaf(wgf, wgf, v);              // fold W-pass +k^2 (exact)
        unsigned int bits = __float_as_uint(v2) |
                            ((unsigned int)flgb[(i0 + j) * TWB + w] << 31);
        ob[(size_t)(i0 + j) * NW] = __uint_as_float(bits);
    }
}

// ---------------------------------------------------------------------------
// K3: min-plus along W, in-place on out, 4 lines/block, 2048 blocks ->
// 8 independent blocks/CU. +k^2 pre-folded by K2; NaN flag in sign bit;
// sqrt + NaN epilogue, float4 stores.
// ---------------------------------------------------------------------------
__global__ __launch_bounds__(256, 8) void k_pass_w(float* __restrict__ out) {
    __shared__ float hs[TWB * HROW];        // 8.3 KB
    __shared__ unsigned int flgw[TWB * NW / 4];  // 2 KB
    int t = threadIdx.x;
    int line0 = blockIdx.x * TWB;
    float* gb = out + (size_t)line0 * NW;

    for (int m = t; m < 512; m += 256) {
        float4 v = *reinterpret_cast<const float4*>(gb + (size_t)m * 4);
        int line = m >> 7;
        int k = (m * 4) & 511;
        unsigned int u0 = __float_as_uint(v.x), u1 = __float_as_uint(v.y);
        unsigned int u2 = __float_as_uint(v.z), u3 = __float_as_uint(v.w);
        flgw[m] = (u0 >> 31) | ((u1 >> 31) << 8) |
                  ((u2 >> 31) << 16) | ((u3 >> 31) << 24);
        float4 o;
        o.x = __uint_as_float(u0 & 0x7fffffffu);
        o.y = __uint_as_float(u1 & 0x7fffffffu);
        o.z = __uint_as_float(u2 & 0x7fffffffu);
        o.w = __uint_as_float(u3 & 0x7fffffffu);
        *reinterpret_cast<float4*>(&hs[line * HROW + k]) = o;
    }
    __syncthreads();

    int line = t & 3, q = t >> 2;
    int i0 = q * 8;
    float best[8], neg2i[8], ifl[8];
#pragma unroll
    for (int j = 0; j < 8; ++j) {
        best[j] = BIG;
        ifl[j] = (float)(i0 + j);
        neg2i[j] = (float)(-2 * (i0 + j));
    }
    eval_minplus(&hs[line * HROW], q, best, neg2i, ifl);

    unsigned int f0 = flgw[(line * NW + i0) >> 2];
    unsigned int f1 = flgw[((line * NW + i0) >> 2) + 1];
    float v[8];
#pragma unroll
    for (int j = 0; j < 8; ++j) {
        float m = fmaf(ifl[j], ifl[j], best[j]);  // exact final d^2
        float sq = sqrtf(m);
        unsigned int fb = (j < 4) ? ((f0 >> (8 * j)) & 1u)
                                  : ((f1 >> (8 * (j - 4))) & 1u);
        v[j] = fb ? __builtin_nanf("") : sq;
    }
    float* op = gb + (size_t)line * NW + i0;
    float4 oa, ob4;
    oa.x = v[0]; oa.y = v[1]; oa.z = v[2]; oa.w = v[3];
    ob4.x = v[4]; ob4.y = v[5]; ob4.z = v[6]; ob4.w = v[7];
    *reinterpret_cast<float4*>(op) = oa;
    *reinterpret_cast<float4*>(op + 4) = ob4;
}

extern "C" void kernel_launch(void* const* d_in, const int* in_sizes, int n_in,
                              void* d_out, int out_size, void* d_ws, size_t ws_size,
                              hipStream_t stream) {
    (void)in_sizes; (void)n_in; (void)out_size; (void)ws_size;
    const float* x = (const float*)d_in[0];
    float* out = (float*)d_out;
    unsigned char* code = (unsigned char*)d_ws;  // 4.2 MB u8 codes

    // K1: x -> u8 codes (d along B + NaN flag)
    k_pass_b<<<dim3(PLANE / 256), 256, 0, stream>>>(x, code);
    // K2: min-plus along H: codes -> out (+w^2 folded, NaN in sign bit)
    k_pass_h<<<dim3(NW / TWB, NB), 256, 0, stream>>>(code, out);
    // K3: min-plus along W, in-place on out, sqrt + NaN mask
    k_pass_w<<<dim3(NB * NH / TWB), 256, 0, stream>>>(out);
}

// Round 17
// 36.428 us; speedup vs baseline: 1.1738x; 1.1738x over previous
//
#include <hip/hip_runtime.h>
#include <math.h>
#include <stdint.h>

#define NB 16
#define NH 512
#define NW 512
#define PLANE (NH * NW)
#define INF_D 1.0e9f
#define INF2 1.0e18f   // == fl(1e9f*1e9f), matches reference d*d rounding
#define BIG 3.0e38f
#define NSEG 64        // 512 / 8
#define TWB 8          // tile width (cols/lines per block)
#define HROW 516       // LDS row stride (floats)

// ---------------------------------------------------------------------------
// One 8-wide segment of the exact min-plus: best[j] = min(best[j],
// h[k] - 2*i_j*k) for k in [ss*8, ss*8+8). Exact ints < 2^24 on the finite
// path -> bit-exact; INF2 absorbs the k^2 shift. min3-pair form.
// ---------------------------------------------------------------------------
__device__ __forceinline__ void eval_seg(const float* __restrict__ hrow,
                                         int ss, float* best,
                                         const float* neg2i) {
    const float* hp = hrow + ss * 8;
    float4 A = *reinterpret_cast<const float4*>(hp);
    float4 B = *reinterpret_cast<const float4*>(hp + 4);
    float s8f = (float)(ss * 8);
#pragma unroll
    for (int j = 0; j < 8; ++j) {
        float n2 = neg2i[j];
        float c0 = fmaf(n2, s8f, A.x);
        float c1 = fmaf(n2, s8f + 1.0f, A.y);
        float c2 = fmaf(n2, s8f + 2.0f, A.z);
        float c3 = fmaf(n2, s8f + 3.0f, A.w);
        float c4 = fmaf(n2, s8f + 4.0f, B.x);
        float c5 = fmaf(n2, s8f + 5.0f, B.y);
        float c6 = fmaf(n2, s8f + 6.0f, B.z);
        float c7 = fmaf(n2, s8f + 7.0f, B.w);
        float bb = fminf(fminf(best[j], c0), c1);
        bb = fminf(fminf(bb, c2), c3);
        bb = fminf(fminf(bb, c4), c5);
        bb = fminf(fminf(bb, c6), c7);
        best[j] = bb;
    }
}

// ---------------------------------------------------------------------------
// Window eval: home+ring1 (static, branch-free), then a sqrt(bmax) window
// evaluated unconditionally. No smin, no serial prune chain. The window is
// conservative (g >= 0 => |i-k| <= sqrt(bmax) required to win) so the
// candidate superset always contains the argmin -> exact min unchanged.
// ---------------------------------------------------------------------------
__device__ __forceinline__ void eval_minplus(const float* __restrict__ hrow,
                                             int q, float* best,
                                             const float* neg2i,
                                             const float* ifl) {
    int s_lo0 = (q > 0) ? q - 1 : 0;
    int s_hi0 = (q < NSEG - 1) ? q + 1 : NSEG - 1;
    for (int ss = s_lo0; ss <= s_hi0; ++ss) eval_seg(hrow, ss, best, neg2i);

    float t0 = fmaf(ifl[0], ifl[0], best[0]);
    float t1 = fmaf(ifl[1], ifl[1], best[1]);
    float t2 = fmaf(ifl[2], ifl[2], best[2]);
    float t3 = fmaf(ifl[3], ifl[3], best[3]);
    float t4 = fmaf(ifl[4], ifl[4], best[4]);
    float t5 = fmaf(ifl[5], ifl[5], best[5]);
    float t6 = fmaf(ifl[6], ifl[6], best[6]);
    float t7 = fmaf(ifl[7], ifl[7], best[7]);
    float m = fmaxf(fmaxf(t0, t1), t2);
    m = fmaxf(fmaxf(m, t3), t4);
    m = fmaxf(fmaxf(m, t5), t6);
    float bmax = fmaxf(m, t7);

    int sw = (int)sqrtf(bmax) + 1;   // conservative (+1 covers 1-ulp sqrt)
    int i0 = q * 8;
    int s_lo = (i0 - sw) >> 3;       // arithmetic shift floors negatives
    int s_hi = (i0 + 7 + sw) >> 3;
    if (s_lo < 0) s_lo = 0;
    if (s_hi > NSEG - 1) s_hi = NSEG - 1;
    for (int ss = s_lo; ss <= s_hi; ++ss) {
        if (ss >= s_lo0 && ss <= s_hi0) continue;  // already done
        eval_seg(hrow, ss, best, neg2i);
    }
}

// ---------------------------------------------------------------------------
// K1: exact B-scan -> u8 codes. 1 col/thread, fully coalesced.
// code = d (0..15 finite, 31 = INF) | (isnan(x) << 7).
// ---------------------------------------------------------------------------
__global__ __launch_bounds__(256, 4) void k_pass_b(const float* __restrict__ x,
                                                   unsigned char* __restrict__ code) {
    int col = blockIdx.x * 256 + threadIdx.x;   // 1024 blocks * 256 == PLANE
    float d0[NB], dd[NB];
    int nanb = 0;
#pragma unroll
    for (int b = 0; b < NB; ++b) {
        float v = x[(size_t)b * PLANE + col];
        nanb |= (isnan(v) ? (1 << b) : 0);
        d0[b] = (v == 0.0f) ? 0.0f : INF_D;     // NaN != 0 -> foreground
    }
    float cc = INF_D;
#pragma unroll
    for (int b = 0; b < NB; ++b) { cc = fminf(cc + 1.0f, d0[b]); dd[b] = cc; }
    cc = INF_D;
#pragma unroll
    for (int b = NB - 1; b >= 0; --b) { cc = fminf(cc + 1.0f, d0[b]); dd[b] = fminf(dd[b], cc); }
#pragma unroll
    for (int b = 0; b < NB; ++b) {
        int di = (dd[b] >= 1.0e8f) ? 31 : (int)dd[b];  // exact small int
        code[(size_t)b * PLANE + col] =
            (unsigned char)(di | (((nanb >> b) & 1) << 7));
    }
}

// ---------------------------------------------------------------------------
// K2: min-plus along H. 512 thr, one (b, 8-wide w tile). Grid (64,16) =
// 1024 blocks -> 4/CU (VGPR<=64, LDS 20.6KB) = 32 waves/CU.
// Writes fl(fl(i^2+best) + w^2) with NaN flag in sign bit.
// ---------------------------------------------------------------------------
__global__ __launch_bounds__(512, 4) void k_pass_h(const unsigned char* __restrict__ code,
                                                   float* __restrict__ out) {
    __shared__ float hs[TWB * HROW];        // 16.1 KB
    __shared__ unsigned int flgw[NH * 2];   // 4 KB
    int t = threadIdx.x;
    int b = blockIdx.y;
    int w0 = blockIdx.x * TWB;
    const unsigned char* gb8 = code + (size_t)b * PLANE + w0;

    for (int m = t; m < 1024; m += 512) {
        int k = m >> 1;
        int bo = (m & 1) * 4;
        unsigned int u = *reinterpret_cast<const unsigned int*>(gb8 + (size_t)k * NW + bo);
        int kk = k * k;
#pragma unroll
        for (int e = 0; e < 4; ++e) {
            int c = (u >> (8 * e)) & 0xFF;
            int dl = c & 31;
            hs[(bo + e) * HROW + k] = (dl == 31) ? INF2 : (float)(dl * dl + kk);
        }
        flgw[m] = (u >> 7) & 0x01010101u;   // packed flags
    }
    __syncthreads();

    int w = t & 7, q = t >> 3;
    int i0 = q * 8;
    float best[8], neg2i[8], ifl[8];
#pragma unroll
    for (int j = 0; j < 8; ++j) {
        best[j] = BIG;
        ifl[j] = (float)(i0 + j);
        neg2i[j] = (float)(-2 * (i0 + j));
    }
    eval_minplus(&hs[w * HROW], q, best, neg2i, ifl);

    const unsigned char* flgb = reinterpret_cast<const unsigned char*>(flgw);
    float wgf = (float)(w0 + w);
    float* ob = out + (size_t)b * PLANE + w0 + w;
#pragma unroll
    for (int j = 0; j < 8; ++j) {
        float v = fmaf(ifl[j], ifl[j], best[j]);   // exact d^2 after B+H
        float v2 = fmaf(wgf, wgf, v);              // fold W-pass +k^2 (exact)
        unsigned int bits = __float_as_uint(v2) |
                            ((unsigned int)flgb[(i0 + j) * TWB + w] << 31);
        ob[(size_t)(i0 + j) * NW] = __uint_as_float(bits);
    }
}

// ---------------------------------------------------------------------------
// K3: min-plus along W, in-place on out, 8 lines/block, 1024 blocks.
// +k^2 pre-folded by K2; NaN flag in sign bit; sqrt + NaN epilogue.
// ---------------------------------------------------------------------------
__global__ __launch_bounds__(512, 4) void k_pass_w(float* __restrict__ out) {
    __shared__ float hs[TWB * HROW];
    __shared__ unsigned int flgw[NH * 2];
    int t = threadIdx.x;
    int line0 = blockIdx.x * TWB;
    float* gb = out + (size_t)line0 * NW;

    for (int m = t; m < 1024; m += 512) {
        float4 v = *reinterpret_cast<const float4*>(gb + (size_t)m * 4);
        int line = m >> 7;
        int k = (m * 4) & 511;
        unsigned int u0 = __float_as_uint(v.x), u1 = __float_as_uint(v.y);
        unsigned int u2 = __float_as_uint(v.z), u3 = __float_as_uint(v.w);
        flgw[m] = (u0 >> 31) | ((u1 >> 31) << 8) |
                  ((u2 >> 31) << 16) | ((u3 >> 31) << 24);
        float4 o;
        o.x = __uint_as_float(u0 & 0x7fffffffu);
        o.y = __uint_as_float(u1 & 0x7fffffffu);
        o.z = __uint_as_float(u2 & 0x7fffffffu);
        o.w = __uint_as_float(u3 & 0x7fffffffu);
        *reinterpret_cast<float4*>(&hs[line * HROW + k]) = o;
    }
    __syncthreads();

    int line = t & 7, q = t >> 3;
    int i0 = q * 8;
    float best[8], neg2i[8], ifl[8];
#pragma unroll
    for (int j = 0; j < 8; ++j) {
        best[j] = BIG;
        ifl[j] = (float)(i0 + j);
        neg2i[j] = (float)(-2 * (i0 + j));
    }
    eval_minplus(&hs[line * HROW], q, best, neg2i, ifl);

    unsigned int f0 = flgw[(line * NW + i0) >> 2];
    unsigned int f1 = flgw[((line * NW + i0) >> 2) + 1];
    float v[8];
#pragma unroll
    for (int j = 0; j < 8; ++j) {
        float m = fmaf(ifl[j], ifl[j], best[j]);  // exact final d^2
        float sq = sqrtf(m);
        unsigned int fb = (j < 4) ? ((f0 >> (8 * j)) & 1u)
                                  : ((f1 >> (8 * (j - 4))) & 1u);
        v[j] = fb ? __builtin_nanf("") : sq;
    }
    float* op = gb + (size_t)line * NW + i0;
    float4 oa, ob4;
    oa.x = v[0]; oa.y = v[1]; oa.z = v[2]; oa.w = v[3];
    ob4.x = v[4]; ob4.y = v[5]; ob4.z = v[6]; ob4.w = v[7];
    *reinterpret_cast<float4*>(op) = oa;
    *reinterpret_cast<float4*>(op + 4) = ob4;
}

extern "C" void kernel_launch(void* const* d_in, const int* in_sizes, int n_in,
                              void* d_out, int out_size, void* d_ws, size_t ws_size,
                              hipStream_t stream) {
    (void)in_sizes; (void)n_in; (void)out_size; (void)ws_size;
    const float* x = (const float*)d_in[0];
    float* out = (float*)d_out;
    unsigned char* code = (unsigned char*)d_ws;  // 4.2 MB u8 codes

    // K1: x -> u8 codes (d along B + NaN flag)
    k_pass_b<<<dim3(PLANE / 256), 256, 0, stream>>>(x, code);
    // K2: min-plus along H: codes -> out (+w^2 folded, NaN in sign bit)
    k_pass_h<<<dim3(NW / TWB, NB), 512, 0, stream>>>(code, out);
    // K3: min-plus along W, in-place on out, sqrt + NaN mask
    k_pass_w<<<dim3(NB * NH / TWB), 512, 0, stream>>>(out);
}